// Round 5
// baseline (763.543 us; speedup 1.0000x reference)
//
#include <hip/hip_runtime.h>

// Problem constants (from reference setup_inputs): Fmap [4,256,32,64,64] f32
constexpr int B_ = 4;
constexpr int C_ = 256;
constexpr int N_ = 32 * 64 * 64;   // 131072 voxels per batch
constexpr int K_ = 256;            // top-k

// Monotone map f32 -> u32: larger float <=> larger uint (total order, -0 < +0)
__device__ __forceinline__ unsigned map_f32(float x) {
  unsigned m = __float_as_uint(x);
  return (m & 0x80000000u) ? ~m : (m | 0x80000000u);
}

// ---------------------------------------------------------------------------
// Kernel 1: per-voxel score (dot over 256 channels), monotone-mapped to u32,
// plus per-batch 128-bin histogram of the top-7 bits (feeds radix select).
// Each thread owns 4 consecutive voxels (float4 loads). Block = 256 thr = 1
// batch-uniform chunk of 1024 voxels.
// ---------------------------------------------------------------------------
__global__ __launch_bounds__(256) void score_hist_kernel(
    const float* __restrict__ F, const float* __restrict__ w,
    unsigned* __restrict__ uscore, int* __restrict__ ghist) {
  __shared__ float sw[C_];
  __shared__ int lh[128];
  sw[threadIdx.x] = w[threadIdx.x];          // blockDim == 256 == C_
  if (threadIdx.x < 128) lh[threadIdx.x] = 0;
  __syncthreads();

  const int t = blockIdx.x * 256 + threadIdx.x;  // 0 .. B*N/4 - 1
  const int b = t >> 15;                          // / (N_/4) = 32768
  const int n = (t & 32767) << 2;                 // voxel base (x4)
  const float* base = F + ((size_t)b * C_) * N_ + n;

  float ax = 0.f, ay = 0.f, az = 0.f, aw = 0.f;
#pragma unroll 2
  for (int c = 0; c < C_; c += 4) {
    float4 f0 = *(const float4*)(base + (size_t)(c + 0) * N_);
    float4 f1 = *(const float4*)(base + (size_t)(c + 1) * N_);
    float4 f2 = *(const float4*)(base + (size_t)(c + 2) * N_);
    float4 f3 = *(const float4*)(base + (size_t)(c + 3) * N_);
    float w0 = sw[c], w1 = sw[c + 1], w2 = sw[c + 2], w3 = sw[c + 3];
    ax += f0.x * w0 + f1.x * w1 + f2.x * w2 + f3.x * w3;
    ay += f0.y * w0 + f1.y * w1 + f2.y * w2 + f3.y * w3;
    az += f0.z * w0 + f1.z * w1 + f2.z * w2 + f3.z * w3;
    aw += f0.w * w0 + f1.w * w1 + f2.w * w2 + f3.w * w3;
  }
  uint4 u;
  u.x = map_f32(ax); u.y = map_f32(ay); u.z = map_f32(az); u.w = map_f32(aw);
  *(uint4*)(uscore + (size_t)b * N_ + n) = u;

  atomicAdd(&lh[u.x >> 25], 1);
  atomicAdd(&lh[u.y >> 25], 1);
  atomicAdd(&lh[u.z >> 25], 1);
  atomicAdd(&lh[u.w >> 25], 1);
  __syncthreads();
  if (threadIdx.x < 128) {
    int v = lh[threadIdx.x];
    if (v) atomicAdd(&ghist[b * 128 + threadIdx.x], v);
  }
}

// ---------------------------------------------------------------------------
// Kernel 2: exact top-K select per batch via radix select on 49-bit keys
//   key(i) = (u[i] << 17) | (N-1-i)   -> all distinct; ties by lower index,
// matching jax.lax.top_k. One block per batch. Pass 0 uses the precomputed
// global histogram, then one compact scan over N; passes 1..6 refine over the
// shrinking candidate list. Emits exactly K indices (order irrelevant).
// ---------------------------------------------------------------------------
__global__ __launch_bounds__(1024) void select_kernel(
    const unsigned* __restrict__ uscore, const int* __restrict__ ghist,
    unsigned* __restrict__ candA, unsigned* __restrict__ candB,
    int* __restrict__ sel) {
  const int b = blockIdx.x;
  const int tid = threadIdx.x;
  const unsigned* u = uscore + (size_t)b * N_;
  int* selb = sel + b * K_;
  unsigned* bufA = candA + (size_t)b * N_;
  unsigned* bufB = candB + (size_t)b * N_;

  __shared__ int hist[128];
  __shared__ int s_chosen, s_remaining, s_selcount, s_nextcount, s_candcount;

  // ---- pass 0: digit = u >> 25 (key bits 48:42), hist already built ----
  if (tid < 128) hist[tid] = ghist[b * 128 + tid];
  if (tid == 0) { s_selcount = 0; s_nextcount = 0; }
  __syncthreads();
  if (tid == 0) {
    int rem = K_, cum = 0, ch = 127;
    for (int d = 127; d >= 0; --d) {
      if (cum + hist[d] >= rem) { ch = d; break; }
      cum += hist[d];
    }
    s_chosen = ch;
    s_remaining = rem - cum;   // still needed from the chosen bin
  }
  __syncthreads();
  {
    const int ch = s_chosen;
    for (int i = tid; i < N_; i += 1024) {
      int d = (int)(u[i] >> 25);
      if (d > ch) {
        int p = atomicAdd(&s_selcount, 1); selb[p] = i;
      } else if (d == ch) {
        int p = atomicAdd(&s_nextcount, 1); bufA[p] = (unsigned)i;
      }
    }
  }
  __syncthreads();
  if (tid == 0) s_candcount = s_nextcount;
  __syncthreads();

  // ---- passes 1..6 over candidates (7-bit digits, shifts 35..0) ----
  int cur = 0;
  for (int pass = 1; pass < 7; ++pass) {
    const int shift = 42 - 7 * pass;
    for (int i = tid; i < 128; i += 1024) hist[i] = 0;
    if (tid == 0) s_nextcount = 0;
    __syncthreads();
    const int cc = s_candcount;
    unsigned* src = cur ? bufB : bufA;
    unsigned* dst = cur ? bufA : bufB;
    for (int i = tid; i < cc; i += 1024) {
      unsigned idx = src[i];
      unsigned long long key =
          ((unsigned long long)u[idx] << 17) | (unsigned)(N_ - 1 - (int)idx);
      int d = (int)((key >> shift) & 127);
      atomicAdd(&hist[d], 1);
    }
    __syncthreads();
    if (tid == 0) {
      int rem = s_remaining, cum = 0, ch = 127;
      for (int d = 127; d >= 0; --d) {
        if (cum + hist[d] >= rem) { ch = d; break; }
        cum += hist[d];
      }
      s_chosen = ch;
      s_remaining = rem - cum;
    }
    __syncthreads();
    const int ch = s_chosen;
    for (int i = tid; i < cc; i += 1024) {
      unsigned idx = src[i];
      unsigned long long key =
          ((unsigned long long)u[idx] << 17) | (unsigned)(N_ - 1 - (int)idx);
      int d = (int)((key >> shift) & 127);
      if (d > ch) {
        int p = atomicAdd(&s_selcount, 1); selb[p] = (int)idx;
      } else if (d == ch) {
        int p = atomicAdd(&s_nextcount, 1); dst[p] = idx;
      }
    }
    __syncthreads();
    if (tid == 0) s_candcount = s_nextcount;
    cur ^= 1;
    __syncthreads();
  }

  // flush: keys are distinct, so s_candcount == s_remaining here
  const int rem = s_remaining, sc = s_selcount;
  unsigned* fin = cur ? bufB : bufA;
  for (int i = tid; i < rem; i += 1024) selb[sc + i] = (int)fin[i];
}

// ---------------------------------------------------------------------------
// Kernel 3: out[b][c] = mean over selected voxels of F[b][c][idx]
// One block per (b,c): 256 threads gather 256 scattered f32, block-reduce.
// ---------------------------------------------------------------------------
__global__ __launch_bounds__(256) void gather_mean_kernel(
    const float* __restrict__ F, const int* __restrict__ sel,
    float* __restrict__ out) {
  const int bc = blockIdx.x;        // b*C + c
  const int b = bc >> 8;
  const int idx = sel[b * K_ + threadIdx.x];
  float v = F[(size_t)bc * N_ + idx];
  for (int off = 32; off; off >>= 1) v += __shfl_down(v, off);
  __shared__ float wsum[4];
  if ((threadIdx.x & 63) == 0) wsum[threadIdx.x >> 6] = v;
  __syncthreads();
  if (threadIdx.x == 0)
    out[bc] = (wsum[0] + wsum[1] + wsum[2] + wsum[3]) * (1.0f / K_);
}

// ---------------------------------------------------------------------------
extern "C" void kernel_launch(void* const* d_in, const int* in_sizes, int n_in,
                              void* d_out, int out_size, void* d_ws, size_t ws_size,
                              hipStream_t stream) {
  const float* F = (const float*)d_in[0];
  const float* w = (const float*)d_in[1];
  // d_in[2] = score_b: constant bias, does not affect top-k set nor output.
  float* out = (float*)d_out;

  char* ws = (char*)d_ws;
  int* ghist = (int*)ws;                                   // 4*128*4 = 2 KiB
  unsigned* uscore = (unsigned*)(ws + 4096);               // B*N*4 = 2 MiB
  unsigned* candA = uscore + (size_t)B_ * N_;              // 2 MiB
  unsigned* candB = candA + (size_t)B_ * N_;               // 2 MiB
  int* sel = (int*)(candB + (size_t)B_ * N_);              // B*K*4 = 4 KiB

  (void)hipMemsetAsync(ghist, 0, B_ * 128 * sizeof(int), stream);
  score_hist_kernel<<<(B_ * N_ / 4) / 256, 256, 0, stream>>>(F, w, uscore, ghist);
  select_kernel<<<B_, 1024, 0, stream>>>(uscore, ghist, candA, candB, sel);
  gather_mean_kernel<<<B_ * C_, 256, 0, stream>>>(F, sel, out);
}